// Round 1
// baseline (1500.026 us; speedup 1.0000x reference)
//
#include <hip/hip_runtime.h>

#define N_NODES 50000
#define N_EDGES 800000

static inline int cdiv(int a, int b) { return (a + b - 1) / b; }

__global__ __launch_bounds__(256) void k_deg_init(float* deg, int n) {
    int i = blockIdx.x * 256 + threadIdx.x;
    if (i < n) deg[i] = 1.0f;
}

__global__ __launch_bounds__(256) void k_deg_count(const int* __restrict__ dst, float* deg, int e) {
    int i = blockIdx.x * 256 + threadIdx.x;
    if (i < e) atomicAdd(&deg[dst[i]], 1.0f);
}

__global__ __launch_bounds__(256) void k_rsqrt(float* deg, int n) {
    int i = blockIdx.x * 256 + threadIdx.x;
    if (i < n) deg[i] = rsqrtf(deg[i]);
}

// C[nrows x NCOL] = A[nrows x 128] @ W[128 x NCOL] (+ bias)
// W staged in LDS (<=64KB). 32 rows/block, 4x4 (or 2x4) register tile/thread.
template <int NCOL, bool BIAS>
__global__ __launch_bounds__(256) void k_gemm(const float* __restrict__ A,
                                              const float* __restrict__ W,
                                              const float* __restrict__ bias,
                                              float* __restrict__ C, int nrows) {
    constexpr int ROWS = 32;
    constexpr int CT = NCOL / 4;      // threads spanning columns (4 cols each)
    constexpr int RG = 256 / CT;      // row groups
    constexpr int RPT = ROWS / RG;    // rows per thread
    __shared__ float Wl[128 * NCOL];

    int t = threadIdx.x;
    for (int i = t * 4; i < 128 * NCOL; i += 256 * 4)
        *(float4*)&Wl[i] = *(const float4*)&W[i];
    __syncthreads();

    int tx = t % CT, ty = t / CT;
    int row0 = blockIdx.x * ROWS + ty * RPT;

    const float* Arow[RPT];
#pragma unroll
    for (int r = 0; r < RPT; r++) {
        int rr = row0 + r;
        if (rr > nrows - 1) rr = nrows - 1;  // clamp for safe loads; store guarded
        Arow[r] = A + (size_t)rr * 128;
    }

    float acc[RPT][4] = {};
    for (int kc = 0; kc < 128; kc += 4) {
        float4 a[RPT];
#pragma unroll
        for (int r = 0; r < RPT; r++) a[r] = *(const float4*)(Arow[r] + kc);
#pragma unroll
        for (int j = 0; j < 4; j++) {
            float4 w = *(const float4*)&Wl[(kc + j) * NCOL + tx * 4];
#pragma unroll
            for (int r = 0; r < RPT; r++) {
                float av = (&a[r].x)[j];
                acc[r][0] += av * w.x;
                acc[r][1] += av * w.y;
                acc[r][2] += av * w.z;
                acc[r][3] += av * w.w;
            }
        }
    }

    float4 bv = make_float4(0.f, 0.f, 0.f, 0.f);
    if (BIAS) bv = *(const float4*)&bias[tx * 4];
#pragma unroll
    for (int r = 0; r < RPT; r++) {
        int rr = row0 + r;
        if (rr < nrows) {
            float4 o = make_float4(acc[r][0] + bv.x, acc[r][1] + bv.y,
                                   acc[r][2] + bv.z, acc[r][3] + bv.w);
            *(float4*)&C[(size_t)rr * NCOL + tx * 4] = o;
        }
    }
}

// agg[n][f] = tmp[n][f] * dinv[n]^2 + bias[f]   (float4 over N*32 vectors)
__global__ __launch_bounds__(256) void k_init_agg(const float4* __restrict__ tmp,
                                                  const float* __restrict__ dinv,
                                                  const float4* __restrict__ bias,
                                                  float4* __restrict__ agg, int nvec) {
    int i = blockIdx.x * 256 + threadIdx.x;
    if (i >= nvec) return;
    float di = dinv[i >> 5];  // 32 float4 per 128-wide row
    float s = di * di;
    float4 tv = tmp[i], b = bias[i & 31];
    agg[i] = make_float4(tv.x * s + b.x, tv.y * s + b.y, tv.z * s + b.z, tv.w * s + b.w);
}

// one wave per edge: agg[dst] += tmp[src] * (dinv[src]*dinv[dst])
__global__ __launch_bounds__(256) void k_scatter(const int* __restrict__ src,
                                                 const int* __restrict__ dst,
                                                 const float* __restrict__ dinv,
                                                 const float* __restrict__ tmp,
                                                 float* __restrict__ agg, int ne) {
    int e = blockIdx.x * 4 + (threadIdx.x >> 6);
    if (e >= ne) return;
    int lane = threadIdx.x & 63;
    int s = src[e], d = dst[e];
    float coef = dinv[s] * dinv[d];
    float v0 = tmp[(size_t)s * 128 + lane];
    float v1 = tmp[(size_t)s * 128 + 64 + lane];
    atomicAdd(&agg[(size_t)d * 128 + lane], v0 * coef);
    atomicAdd(&agg[(size_t)d * 128 + 64 + lane], v1 * coef);
}

// out[i] = relu(agg[i]) + res[i]
__global__ __launch_bounds__(256) void k_relu_res(const float4* __restrict__ agg,
                                                  const float4* __restrict__ res,
                                                  float4* __restrict__ out, int nvec) {
    int i = blockIdx.x * 256 + threadIdx.x;
    if (i >= nvec) return;
    float4 a = agg[i], r = res[i];
    out[i] = make_float4(fmaxf(a.x, 0.f) + r.x, fmaxf(a.y, 0.f) + r.y,
                         fmaxf(a.z, 0.f) + r.z, fmaxf(a.w, 0.f) + r.w);
}

extern "C" void kernel_launch(void* const* d_in, const int* in_sizes, int n_in,
                              void* d_out, int out_size, void* d_ws, size_t ws_size,
                              hipStream_t stream) {
    const float* x  = (const float*)d_in[0];
    const int* eidx = (const int*)d_in[1];
    const float* W0 = (const float*)d_in[2];
    const float* b0 = (const float*)d_in[3];
    const float* W1 = (const float*)d_in[4];
    const float* b1 = (const float*)d_in[5];
    const float* W2 = (const float*)d_in[6];
    const float* b2 = (const float*)d_in[7];
    const float* Wo = (const float*)d_in[8];
    const float* bo = (const float*)d_in[9];
    float* out = (float*)d_out;

    const int N = N_NODES, E = N_EDGES;
    const int* srcI = eidx;      // edge_index[0]
    const int* dstI = eidx + E;  // edge_index[1]

    char* ws = (char*)d_ws;
    float* dinv = (float*)ws; ws += ((size_t)(N * 4 + 255) / 256) * 256;
    float* tmp  = (float*)ws; ws += (size_t)N * 128 * 4;
    float* hA   = (float*)ws; ws += (size_t)N * 128 * 4;
    float* hB   = (float*)ws;

    const int nvec = N * 128 / 4;  // 1,600,000 float4s
    dim3 b256(256);

    // normalization coefficients
    k_deg_init<<<cdiv(N, 256), b256, 0, stream>>>(dinv, N);
    k_deg_count<<<cdiv(E, 256), b256, 0, stream>>>(dstI, dinv, E);
    k_rsqrt<<<cdiv(N, 256), b256, 0, stream>>>(dinv, N);

    // layer 0: hA = relu(conv(x, W0, b0)) + x
    k_gemm<128, false><<<cdiv(N, 32), b256, 0, stream>>>(x, W0, nullptr, tmp, N);
    k_init_agg<<<cdiv(nvec, 256), b256, 0, stream>>>((const float4*)tmp, dinv, (const float4*)b0, (float4*)hA, nvec);
    k_scatter<<<cdiv(E, 4), b256, 0, stream>>>(srcI, dstI, dinv, tmp, hA, E);
    k_relu_res<<<cdiv(nvec, 256), b256, 0, stream>>>((const float4*)hA, (const float4*)x, (float4*)hA, nvec);

    // layer 1: hB = relu(conv(hA, W1, b1)) + hA
    k_gemm<128, false><<<cdiv(N, 32), b256, 0, stream>>>(hA, W1, nullptr, tmp, N);
    k_init_agg<<<cdiv(nvec, 256), b256, 0, stream>>>((const float4*)tmp, dinv, (const float4*)b1, (float4*)hB, nvec);
    k_scatter<<<cdiv(E, 4), b256, 0, stream>>>(srcI, dstI, dinv, tmp, hB, E);
    k_relu_res<<<cdiv(nvec, 256), b256, 0, stream>>>((const float4*)hB, (const float4*)hA, (float4*)hB, nvec);

    // layer 2: hA = relu(conv(hB, W2, b2)) + hB
    k_gemm<128, false><<<cdiv(N, 32), b256, 0, stream>>>(hB, W2, nullptr, tmp, N);
    k_init_agg<<<cdiv(nvec, 256), b256, 0, stream>>>((const float4*)tmp, dinv, (const float4*)b2, (float4*)hA, nvec);
    k_scatter<<<cdiv(E, 4), b256, 0, stream>>>(srcI, dstI, dinv, tmp, hA, E);
    k_relu_res<<<cdiv(nvec, 256), b256, 0, stream>>>((const float4*)hA, (const float4*)hB, (float4*)hA, nvec);

    // output projection: out = hA @ W_out + b_out
    k_gemm<64, true><<<cdiv(N, 32), b256, 0, stream>>>(hA, Wo, bo, out, N);
}

// Round 2
// 721.250 us; speedup vs baseline: 2.0798x; 2.0798x over previous
//
#include <hip/hip_runtime.h>

#define N_NODES 50000
#define N_EDGES 800000

static inline int cdiv(int a, int b) { return (a + b - 1) / b; }

// ---------------- degree / normalization ----------------

__global__ __launch_bounds__(256) void k_zero_int(int* p, int n) {
    int i = blockIdx.x * 256 + threadIdx.x;
    if (i < n) p[i] = 0;
}

__global__ __launch_bounds__(256) void k_count(const int* __restrict__ dst, int* cnt, int e) {
    int i = blockIdx.x * 256 + threadIdx.x;
    if (i < e) atomicAdd(&cnt[dst[i]], 1);
}

__global__ __launch_bounds__(256) void k_dinv(const int* __restrict__ cnt, float* dinv, int n) {
    int i = blockIdx.x * 256 + threadIdx.x;
    if (i < n) dinv[i] = rsqrtf((float)cnt[i] + 1.0f);
}

// ---------------- CSR build (counting sort by dst) ----------------

__global__ __launch_bounds__(512) void k_block_sum(const int* __restrict__ cnt, int* bsum, int n) {
    __shared__ int sh[512];
    int i = blockIdx.x * 512 + threadIdx.x;
    sh[threadIdx.x] = (i < n) ? cnt[i] : 0;
    __syncthreads();
    for (int off = 256; off > 0; off >>= 1) {
        if (threadIdx.x < off) sh[threadIdx.x] += sh[threadIdx.x + off];
        __syncthreads();
    }
    if (threadIdx.x == 0) bsum[blockIdx.x] = sh[0];
}

__global__ void k_scan_bsum(const int* __restrict__ bsum, int* boff, int nb, int* rowptr, int n, int e) {
    if (blockIdx.x == 0 && threadIdx.x == 0) {
        int acc = 0;
        for (int i = 0; i < nb; i++) { boff[i] = acc; acc += bsum[i]; }
        rowptr[n] = e;
    }
}

__global__ __launch_bounds__(512) void k_scan_block(const int* __restrict__ cnt,
                                                    const int* __restrict__ boff,
                                                    int* rowptr, int* cursor, int n) {
    __shared__ int sh[512];
    int t = threadIdx.x;
    int i = blockIdx.x * 512 + t;
    int v = (i < n) ? cnt[i] : 0;
    sh[t] = v;
    __syncthreads();
    for (int off = 1; off < 512; off <<= 1) {
        int add = (t >= off) ? sh[t - off] : 0;
        __syncthreads();
        sh[t] += add;
        __syncthreads();
    }
    if (i < n) {
        rowptr[i] = sh[t] - v + boff[blockIdx.x];  // exclusive scan
        cursor[i] = 0;
    }
}

__global__ __launch_bounds__(256) void k_fill(const int* __restrict__ src, const int* __restrict__ dst,
                                              const float* __restrict__ dinv,
                                              const int* __restrict__ rowptr, int* cursor,
                                              int2* ed, int e) {
    int i = blockIdx.x * 256 + threadIdx.x;
    if (i >= e) return;
    int d = dst[i], s = src[i];
    int pos = rowptr[d] + atomicAdd(&cursor[d], 1);
    float c = dinv[s] * dinv[d];
    ed[pos] = make_int2(s, __float_as_int(c));
}

// ---------------- GEMM: C[nrows x NCOL] = A[nrows x 128] @ W[128 x NCOL] (+bias) ----------------

template <int NCOL, bool BIAS>
__global__ __launch_bounds__(256) void k_gemm(const float* __restrict__ A,
                                              const float* __restrict__ W,
                                              const float* __restrict__ bias,
                                              float* __restrict__ C, int nrows) {
    constexpr int ROWS = 32;
    constexpr int CT = NCOL / 4;
    constexpr int RG = 256 / CT;
    constexpr int RPT = ROWS / RG;
    __shared__ float Wl[128 * NCOL];

    int t = threadIdx.x;
    for (int i = t * 4; i < 128 * NCOL; i += 256 * 4)
        *(float4*)&Wl[i] = *(const float4*)&W[i];
    __syncthreads();

    int tx = t % CT, ty = t / CT;
    int row0 = blockIdx.x * ROWS + ty * RPT;

    const float* Arow[RPT];
#pragma unroll
    for (int r = 0; r < RPT; r++) {
        int rr = row0 + r;
        if (rr > nrows - 1) rr = nrows - 1;
        Arow[r] = A + (size_t)rr * 128;
    }

    float acc[RPT][4] = {};
    for (int kc = 0; kc < 128; kc += 4) {
        float4 a[RPT];
#pragma unroll
        for (int r = 0; r < RPT; r++) a[r] = *(const float4*)(Arow[r] + kc);
#pragma unroll
        for (int j = 0; j < 4; j++) {
            float4 w = *(const float4*)&Wl[(kc + j) * NCOL + tx * 4];
#pragma unroll
            for (int r = 0; r < RPT; r++) {
                float av = (&a[r].x)[j];
                acc[r][0] += av * w.x;
                acc[r][1] += av * w.y;
                acc[r][2] += av * w.z;
                acc[r][3] += av * w.w;
            }
        }
    }

    float4 bv = make_float4(0.f, 0.f, 0.f, 0.f);
    if (BIAS) bv = *(const float4*)&bias[tx * 4];
#pragma unroll
    for (int r = 0; r < RPT; r++) {
        int rr = row0 + r;
        if (rr < nrows) {
            float4 o = make_float4(acc[r][0] + bv.x, acc[r][1] + bv.y,
                                   acc[r][2] + bv.z, acc[r][3] + bv.w);
            *(float4*)&C[(size_t)rr * NCOL + tx * 4] = o;
        }
    }
}

// ---------------- fused gather: agg = sum_e tmp[src]*coef + tmp[d]*dinv^2 + b; out = relu(agg)+res ----------------

__global__ __launch_bounds__(256) void k_gather(const float* __restrict__ tmp,
                                                const int* __restrict__ rowptr,
                                                const int2* __restrict__ ed,
                                                const float* __restrict__ dinv,
                                                const float* __restrict__ bias,
                                                const float* __restrict__ res,
                                                float* __restrict__ out, int n) {
    int node = blockIdx.x * 4 + (threadIdx.x >> 6);
    if (node >= n) return;
    int lane = threadIdx.x & 63;

    int beg = rowptr[node], end = rowptr[node + 1];
    const float2* T = (const float2*)tmp;

    float ax = 0.f, ay = 0.f;
    int e = beg;
    for (; e + 1 < end; e += 2) {
        int2 m0 = ed[e], m1 = ed[e + 1];
        float2 t0 = T[(size_t)m0.x * 64 + lane];
        float2 t1 = T[(size_t)m1.x * 64 + lane];
        float c0 = __int_as_float(m0.y), c1 = __int_as_float(m1.y);
        ax += t0.x * c0 + t1.x * c1;
        ay += t0.y * c0 + t1.y * c1;
    }
    if (e < end) {
        int2 m = ed[e];
        float2 t = T[(size_t)m.x * 64 + lane];
        float c = __int_as_float(m.y);
        ax += t.x * c;
        ay += t.y * c;
    }

    float di = dinv[node];
    float sc = di * di;
    float2 ts = T[(size_t)node * 64 + lane];
    float2 b = ((const float2*)bias)[lane];
    ax += ts.x * sc + b.x;
    ay += ts.y * sc + b.y;

    float2 r = ((const float2*)res)[(size_t)node * 64 + lane];
    float2 o = make_float2(fmaxf(ax, 0.f) + r.x, fmaxf(ay, 0.f) + r.y);
    ((float2*)out)[(size_t)node * 64 + lane] = o;
}

// ---------------- launch ----------------

extern "C" void kernel_launch(void* const* d_in, const int* in_sizes, int n_in,
                              void* d_out, int out_size, void* d_ws, size_t ws_size,
                              hipStream_t stream) {
    const float* x  = (const float*)d_in[0];
    const int* eidx = (const int*)d_in[1];
    const float* W0 = (const float*)d_in[2];
    const float* b0 = (const float*)d_in[3];
    const float* W1 = (const float*)d_in[4];
    const float* b1 = (const float*)d_in[5];
    const float* W2 = (const float*)d_in[6];
    const float* b2 = (const float*)d_in[7];
    const float* Wo = (const float*)d_in[8];
    const float* bo = (const float*)d_in[9];
    float* out = (float*)d_out;

    const int N = N_NODES, E = N_EDGES;
    const int* srcI = eidx;
    const int* dstI = eidx + E;

    const int NB512 = cdiv(N, 512);  // 98 scan blocks

    char* ws = (char*)d_ws;
    auto alloc = [&](size_t bytes) { char* p = ws; ws += (bytes + 255) / 256 * 256; return p; };
    int*   cnt    = (int*)alloc((size_t)N * 4);
    int*   cursor = (int*)alloc((size_t)N * 4);
    int*   rowptr = (int*)alloc((size_t)(N + 1) * 4);
    int*   bsum   = (int*)alloc((size_t)NB512 * 4);
    int*   boff   = (int*)alloc((size_t)NB512 * 4);
    float* dinv   = (float*)alloc((size_t)N * 4);
    int2*  ed     = (int2*)alloc((size_t)E * 8);
    float* tmp    = (float*)alloc((size_t)N * 128 * 4);
    float* hA     = (float*)alloc((size_t)N * 128 * 4);
    float* hB     = (float*)alloc((size_t)N * 128 * 4);

    dim3 b256(256), b512(512);

    // degree + normalization + CSR build
    k_zero_int<<<cdiv(N, 256), b256, 0, stream>>>(cnt, N);
    k_count<<<cdiv(E, 256), b256, 0, stream>>>(dstI, cnt, E);
    k_dinv<<<cdiv(N, 256), b256, 0, stream>>>(cnt, dinv, N);
    k_block_sum<<<NB512, b512, 0, stream>>>(cnt, bsum, N);
    k_scan_bsum<<<1, 64, 0, stream>>>(bsum, boff, NB512, rowptr, N, E);
    k_scan_block<<<NB512, b512, 0, stream>>>(cnt, boff, rowptr, cursor, N);
    k_fill<<<cdiv(E, 256), b256, 0, stream>>>(srcI, dstI, dinv, rowptr, cursor, ed, E);

    const int gatherGrid = cdiv(N, 4);

    // layer 0: hA = relu(conv(x)) + x
    k_gemm<128, false><<<cdiv(N, 32), b256, 0, stream>>>(x, W0, nullptr, tmp, N);
    k_gather<<<gatherGrid, b256, 0, stream>>>(tmp, rowptr, ed, dinv, b0, x, hA, N);

    // layer 1: hB = relu(conv(hA)) + hA
    k_gemm<128, false><<<cdiv(N, 32), b256, 0, stream>>>(hA, W1, nullptr, tmp, N);
    k_gather<<<gatherGrid, b256, 0, stream>>>(tmp, rowptr, ed, dinv, b1, hA, hB, N);

    // layer 2: hA = relu(conv(hB)) + hB
    k_gemm<128, false><<<cdiv(N, 32), b256, 0, stream>>>(hB, W2, nullptr, tmp, N);
    k_gather<<<gatherGrid, b256, 0, stream>>>(tmp, rowptr, ed, dinv, b2, hB, hA, N);

    // output projection
    k_gemm<64, true><<<cdiv(N, 32), b256, 0, stream>>>(hA, Wo, bo, out, N);
}

// Round 3
// 434.810 us; speedup vs baseline: 3.4498x; 1.6588x over previous
//
#include <hip/hip_runtime.h>

#define N_NODES 50000
#define N_EDGES 800000

static inline int cdiv(int a, int b) { return (a + b - 1) / b; }

typedef __attribute__((ext_vector_type(8))) short s8vec;   // 8 x bf16 (4 VGPRs)
typedef __attribute__((ext_vector_type(4))) float f32x4;   // MFMA accumulator

// fp32 -> bf16 round-to-nearest-even
__device__ inline ushort f2b(float f) {
    uint u = __float_as_uint(f);
    uint r = (u + 0x7fffu + ((u >> 16) & 1u)) >> 16;
    return (ushort)r;
}
__device__ inline float b2f_lo(uint v) { return __uint_as_float(v << 16); }
__device__ inline float b2f_hi(uint v) { return __uint_as_float(v & 0xffff0000u); }

// ---------------- degree / normalization ----------------

__global__ __launch_bounds__(256) void k_zero_int(int* p, int n) {
    int i = blockIdx.x * 256 + threadIdx.x;
    if (i < n) p[i] = 0;
}

__global__ __launch_bounds__(256) void k_count(const int* __restrict__ dst, int* cnt, int e) {
    int i = blockIdx.x * 256 + threadIdx.x;
    if (i < e) atomicAdd(&cnt[dst[i]], 1);
}

__global__ __launch_bounds__(256) void k_dinv(const int* __restrict__ cnt, float* dinv, int n) {
    int i = blockIdx.x * 256 + threadIdx.x;
    if (i < n) dinv[i] = rsqrtf((float)cnt[i] + 1.0f);
}

// ---------------- CSR build (counting sort by dst) ----------------

__global__ __launch_bounds__(512) void k_block_sum(const int* __restrict__ cnt, int* bsum, int n) {
    __shared__ int sh[512];
    int i = blockIdx.x * 512 + threadIdx.x;
    sh[threadIdx.x] = (i < n) ? cnt[i] : 0;
    __syncthreads();
    for (int off = 256; off > 0; off >>= 1) {
        if (threadIdx.x < off) sh[threadIdx.x] += sh[threadIdx.x + off];
        __syncthreads();
    }
    if (threadIdx.x == 0) bsum[blockIdx.x] = sh[0];
}

__global__ void k_scan_bsum(const int* __restrict__ bsum, int* boff, int nb, int* rowptr, int n, int e) {
    if (blockIdx.x == 0 && threadIdx.x == 0) {
        int acc = 0;
        for (int i = 0; i < nb; i++) { boff[i] = acc; acc += bsum[i]; }
        rowptr[n] = e;
    }
}

__global__ __launch_bounds__(512) void k_scan_block(const int* __restrict__ cnt,
                                                    const int* __restrict__ boff,
                                                    int* rowptr, int* cursor, int n) {
    __shared__ int sh[512];
    int t = threadIdx.x;
    int i = blockIdx.x * 512 + t;
    int v = (i < n) ? cnt[i] : 0;
    sh[t] = v;
    __syncthreads();
    for (int off = 1; off < 512; off <<= 1) {
        int add = (t >= off) ? sh[t - off] : 0;
        __syncthreads();
        sh[t] += add;
        __syncthreads();
    }
    if (i < n) {
        rowptr[i] = sh[t] - v + boff[blockIdx.x];
        cursor[i] = 0;
    }
}

__global__ __launch_bounds__(256) void k_fill(const int* __restrict__ src, const int* __restrict__ dst,
                                              const float* __restrict__ dinv,
                                              const int* __restrict__ rowptr, int* cursor,
                                              int2* ed, int e) {
    int i = blockIdx.x * 256 + threadIdx.x;
    if (i >= e) return;
    int d = dst[i], s = src[i];
    int pos = rowptr[d] + atomicAdd(&cursor[d], 1);
    float c = dinv[s] * dinv[d];
    ed[pos] = make_int2(s, __float_as_int(c));
}

// ---------------- conversions ----------------

// fp32[4] -> bf16[4] packed as uint2
__global__ __launch_bounds__(256) void k_cvt(const float4* __restrict__ X, uint2* __restrict__ Xb, int nvec) {
    int i = blockIdx.x * 256 + threadIdx.x;
    if (i >= nvec) return;
    float4 v = X[i];
    Xb[i] = make_uint2((uint)f2b(v.x) | ((uint)f2b(v.y) << 16),
                       (uint)f2b(v.z) | ((uint)f2b(v.w) << 16));
}

// Wt[n*K + k] = bf16(W[k*Ncols + n])   (transpose + convert; tiny)
__global__ __launch_bounds__(256) void k_wt(const float* __restrict__ W, ushort* __restrict__ Wt,
                                            int K, int Ncols) {
    int i = blockIdx.x * 256 + threadIdx.x;
    if (i >= K * Ncols) return;
    int nn = i / K, k = i - nn * K;
    Wt[i] = f2b(W[(size_t)k * Ncols + nn]);
}

// ---------------- MFMA GEMM: C[n x NCOL] = A[n x 128](bf16) @ Wt^T ----------------
// Wt is [NCOL x 128] bf16 (pre-transposed). Hidden layers write bf16 [n x 128];
// final layer writes fp32 + bias to d_out.

template <int NCOL, bool OUT_F32>
__global__ __launch_bounds__(256) void k_mm(const ushort* __restrict__ A,
                                            const ushort* __restrict__ Wt,
                                            const float* __restrict__ bias,
                                            void* __restrict__ Cv, int n) {
    constexpr int NT = NCOL / 16;
    int wave = threadIdx.x >> 6;
    int lane = threadIdx.x & 63;
    int quad = lane >> 4;
    int lm = lane & 15;
    int row0 = blockIdx.x * 64 + wave * 16;

    int rA = row0 + lm;
    if (rA > n - 1) rA = n - 1;                 // clamp loads; stores guarded
    const ushort* Ap = A + (size_t)rA * 128 + quad * 8;

    f32x4 acc[NT];
#pragma unroll
    for (int t = 0; t < NT; t++) acc[t] = (f32x4){0.f, 0.f, 0.f, 0.f};

    for (int kc = 0; kc < 128; kc += 32) {
        s8vec af = *(const s8vec*)(Ap + kc);
#pragma unroll
        for (int t = 0; t < NT; t++) {
            s8vec bf = *(const s8vec*)(Wt + (size_t)(t * 16 + lm) * 128 + kc + quad * 8);
            acc[t] = __builtin_amdgcn_mfma_f32_16x16x32_bf16(af, bf, acc[t], 0, 0, 0);
        }
    }

    // C/D layout: col = lane&15, row = quad*4 + reg   [m89-verified]
#pragma unroll
    for (int t = 0; t < NT; t++) {
        int col = t * 16 + lm;
        float bv = OUT_F32 ? bias[col] : 0.f;
#pragma unroll
        for (int i = 0; i < 4; i++) {
            int r = row0 + quad * 4 + i;
            if (r < n) {
                if (OUT_F32)
                    ((float*)Cv)[(size_t)r * NCOL + col] = acc[t][i] + bv;
                else
                    ((ushort*)Cv)[(size_t)r * 128 + col] = f2b(acc[t][i]);
            }
        }
    }
}

// ---------------- fused gather (bf16 features) ----------------
// agg = sum_e tmp[src]*coef + tmp[node]*dinv^2 + bias; out = bf16(relu(agg) + res)

__global__ __launch_bounds__(256) void k_gatherb(const uint* __restrict__ T,     // [n x 64] bf16-pairs
                                                 const int* __restrict__ rowptr,
                                                 const int2* __restrict__ ed,
                                                 const float* __restrict__ dinv,
                                                 const float* __restrict__ bias,
                                                 const uint* __restrict__ res,   // [n x 64] bf16-pairs
                                                 uint* __restrict__ out, int n) {
    int node = blockIdx.x * 4 + (threadIdx.x >> 6);
    if (node >= n) return;
    int lane = threadIdx.x & 63;

    int beg = rowptr[node], end = rowptr[node + 1];
    float ax = 0.f, ay = 0.f;
    int e = beg;
    for (; e + 1 < end; e += 2) {
        int2 m0 = ed[e], m1 = ed[e + 1];
        uint v0 = T[(size_t)m0.x * 64 + lane];
        uint v1 = T[(size_t)m1.x * 64 + lane];
        float c0 = __int_as_float(m0.y), c1 = __int_as_float(m1.y);
        ax += b2f_lo(v0) * c0 + b2f_lo(v1) * c1;
        ay += b2f_hi(v0) * c0 + b2f_hi(v1) * c1;
    }
    if (e < end) {
        int2 m = ed[e];
        uint v = T[(size_t)m.x * 64 + lane];
        float c = __int_as_float(m.y);
        ax += b2f_lo(v) * c;
        ay += b2f_hi(v) * c;
    }

    float di = dinv[node];
    float sc = di * di;
    uint vs = T[(size_t)node * 64 + lane];
    ax += b2f_lo(vs) * sc + bias[lane * 2];
    ay += b2f_hi(vs) * sc + bias[lane * 2 + 1];

    uint rv = res[(size_t)node * 64 + lane];
    float ox = fmaxf(ax, 0.f) + b2f_lo(rv);
    float oy = fmaxf(ay, 0.f) + b2f_hi(rv);
    out[(size_t)node * 64 + lane] = (uint)f2b(ox) | ((uint)f2b(oy) << 16);
}

// ---------------- launch ----------------

extern "C" void kernel_launch(void* const* d_in, const int* in_sizes, int n_in,
                              void* d_out, int out_size, void* d_ws, size_t ws_size,
                              hipStream_t stream) {
    const float* x  = (const float*)d_in[0];
    const int* eidx = (const int*)d_in[1];
    const float* W0 = (const float*)d_in[2];
    const float* b0 = (const float*)d_in[3];
    const float* W1 = (const float*)d_in[4];
    const float* b1 = (const float*)d_in[5];
    const float* W2 = (const float*)d_in[6];
    const float* b2 = (const float*)d_in[7];
    const float* Wo = (const float*)d_in[8];
    const float* bo = (const float*)d_in[9];
    float* out = (float*)d_out;

    const int N = N_NODES, E = N_EDGES;
    const int* srcI = eidx;
    const int* dstI = eidx + E;
    const int NB512 = cdiv(N, 512);

    char* ws = (char*)d_ws;
    auto alloc = [&](size_t bytes) { char* p = ws; ws += (bytes + 255) / 256 * 256; return p; };
    int*    cnt    = (int*)alloc((size_t)N * 4);
    int*    cursor = (int*)alloc((size_t)N * 4);
    int*    rowptr = (int*)alloc((size_t)(N + 1) * 4);
    int*    bsum   = (int*)alloc((size_t)NB512 * 4);
    int*    boff   = (int*)alloc((size_t)NB512 * 4);
    float*  dinv   = (float*)alloc((size_t)N * 4);
    int2*   ed     = (int2*)alloc((size_t)E * 8);
    ushort* xb     = (ushort*)alloc((size_t)N * 128 * 2);
    ushort* tmpb   = (ushort*)alloc((size_t)N * 128 * 2);
    ushort* hAb    = (ushort*)alloc((size_t)N * 128 * 2);
    ushort* hBb    = (ushort*)alloc((size_t)N * 128 * 2);
    ushort* Wt0    = (ushort*)alloc(128 * 128 * 2);
    ushort* Wt1    = (ushort*)alloc(128 * 128 * 2);
    ushort* Wt2    = (ushort*)alloc(128 * 128 * 2);
    ushort* Wto    = (ushort*)alloc(64 * 128 * 2);

    dim3 b256(256), b512(512);

    // degree + normalization + CSR build
    k_zero_int<<<cdiv(N, 256), b256, 0, stream>>>(cnt, N);
    k_count<<<cdiv(E, 256), b256, 0, stream>>>(dstI, cnt, E);
    k_dinv<<<cdiv(N, 256), b256, 0, stream>>>(cnt, dinv, N);
    k_block_sum<<<NB512, b512, 0, stream>>>(cnt, bsum, N);
    k_scan_bsum<<<1, 64, 0, stream>>>(bsum, boff, NB512, rowptr, N, E);
    k_scan_block<<<NB512, b512, 0, stream>>>(cnt, boff, rowptr, cursor, N);
    k_fill<<<cdiv(E, 256), b256, 0, stream>>>(srcI, dstI, dinv, rowptr, cursor, ed, E);

    // conversions
    const int nvec = N * 128 / 4;
    k_cvt<<<cdiv(nvec, 256), b256, 0, stream>>>((const float4*)x, (uint2*)xb, nvec);
    k_wt<<<cdiv(128 * 128, 256), b256, 0, stream>>>(W0, Wt0, 128, 128);
    k_wt<<<cdiv(128 * 128, 256), b256, 0, stream>>>(W1, Wt1, 128, 128);
    k_wt<<<cdiv(128 * 128, 256), b256, 0, stream>>>(W2, Wt2, 128, 128);
    k_wt<<<cdiv(64 * 128, 256), b256, 0, stream>>>(Wo, Wto, 128, 64);

    const int mmGrid = cdiv(N, 64);
    const int gGrid  = cdiv(N, 4);

    // layer 0
    k_mm<128, false><<<mmGrid, b256, 0, stream>>>(xb, Wt0, nullptr, tmpb, N);
    k_gatherb<<<gGrid, b256, 0, stream>>>((const uint*)tmpb, rowptr, ed, dinv, b0, (const uint*)xb, (uint*)hAb, N);

    // layer 1
    k_mm<128, false><<<mmGrid, b256, 0, stream>>>(hAb, Wt1, nullptr, tmpb, N);
    k_gatherb<<<gGrid, b256, 0, stream>>>((const uint*)tmpb, rowptr, ed, dinv, b1, (const uint*)hAb, (uint*)hBb, N);

    // layer 2
    k_mm<128, false><<<mmGrid, b256, 0, stream>>>(hBb, Wt2, nullptr, tmpb, N);
    k_gatherb<<<gGrid, b256, 0, stream>>>((const uint*)tmpb, rowptr, ed, dinv, b2, (const uint*)hBb, (uint*)hAb, N);

    // output projection (fp32 out + bias)
    k_mm<64, true><<<mmGrid, b256, 0, stream>>>(hAb, Wto, bo, out, N);
}

// Round 4
// 338.146 us; speedup vs baseline: 4.4360x; 1.2859x over previous
//
#include <hip/hip_runtime.h>

#define N_NODES 50000
#define N_EDGES 800000

static inline int cdiv(int a, int b) { return (a + b - 1) / b; }

typedef __attribute__((ext_vector_type(8))) short s8vec;   // 8 x bf16 (4 VGPRs)
typedef __attribute__((ext_vector_type(4))) float f32x4;   // MFMA accumulator

// fp32 -> bf16 round-to-nearest-even
__device__ inline ushort f2b(float f) {
    uint u = __float_as_uint(f);
    uint r = (u + 0x7fffu + ((u >> 16) & 1u)) >> 16;
    return (ushort)r;
}
__device__ inline float b2f_lo(uint v) { return __uint_as_float(v << 16); }
__device__ inline float b2f_hi(uint v) { return __uint_as_float(v & 0xffff0000u); }

// ---------------- degree / CSR build ----------------

__global__ __launch_bounds__(256) void k_zero_int(int* p, int n) {
    int i = blockIdx.x * 256 + threadIdx.x;
    if (i < n) p[i] = 0;
}

__global__ __launch_bounds__(256) void k_count(const int* __restrict__ dst, int* cnt, int e) {
    int i = blockIdx.x * 256 + threadIdx.x;
    if (i < e) atomicAdd(&cnt[dst[i]], 1);
}

__global__ __launch_bounds__(512) void k_block_sum(const int* __restrict__ cnt, int* bsum, int n) {
    __shared__ int sh[512];
    int i = blockIdx.x * 512 + threadIdx.x;
    sh[threadIdx.x] = (i < n) ? cnt[i] : 0;
    __syncthreads();
    for (int off = 256; off > 0; off >>= 1) {
        if (threadIdx.x < off) sh[threadIdx.x] += sh[threadIdx.x + off];
        __syncthreads();
    }
    if (threadIdx.x == 0) bsum[blockIdx.x] = sh[0];
}

// parallel exclusive scan of block sums (nb <= 128), one block of 128 threads
__global__ __launch_bounds__(128) void k_scan_bsum(const int* __restrict__ bsum, int* boff,
                                                   int nb, int* rowptr, int n, int e) {
    __shared__ int sh[128];
    int t = threadIdx.x;
    int v = (t < nb) ? bsum[t] : 0;
    sh[t] = v;
    __syncthreads();
    for (int off = 1; off < 128; off <<= 1) {
        int add = (t >= off) ? sh[t - off] : 0;
        __syncthreads();
        sh[t] += add;
        __syncthreads();
    }
    if (t < nb) boff[t] = sh[t] - v;   // exclusive
    if (t == 0) rowptr[n] = e;
}

// per-block exclusive scan + rowptr; also cursor=0 and dinv = rsqrt(deg+1)
__global__ __launch_bounds__(512) void k_scan_block(const int* __restrict__ cnt,
                                                    const int* __restrict__ boff,
                                                    int* rowptr, int* cursor, float* dinv, int n) {
    __shared__ int sh[512];
    int t = threadIdx.x;
    int i = blockIdx.x * 512 + t;
    int v = (i < n) ? cnt[i] : 0;
    sh[t] = v;
    __syncthreads();
    for (int off = 1; off < 512; off <<= 1) {
        int add = (t >= off) ? sh[t - off] : 0;
        __syncthreads();
        sh[t] += add;
        __syncthreads();
    }
    if (i < n) {
        rowptr[i] = sh[t] - v + boff[blockIdx.x];
        cursor[i] = 0;
        dinv[i] = rsqrtf((float)v + 1.0f);
    }
}

__global__ __launch_bounds__(256) void k_fill(const int* __restrict__ src, const int* __restrict__ dst,
                                              const float* __restrict__ dinv,
                                              const int* __restrict__ rowptr, int* cursor,
                                              uint2* ed, int e) {
    int i = blockIdx.x * 256 + threadIdx.x;
    if (i >= e) return;
    int d = dst[i], s = src[i];
    int pos = rowptr[d] + atomicAdd(&cursor[d], 1);
    float c = dinv[s] * dinv[d];
    ed[pos] = make_uint2((uint)s, __float_as_uint(c));
}

// ---------------- all-weight transpose+convert in one kernel ----------------
// Wt[n*128 + k] = bf16(W[k*Ncols + n]); sizes: 3x(128x128) + 1x(128x64)

__global__ __launch_bounds__(256) void k_wt_all(const float* __restrict__ W0, const float* __restrict__ W1,
                                                const float* __restrict__ W2, const float* __restrict__ Wo,
                                                ushort* Wt0, ushort* Wt1, ushort* Wt2, ushort* Wto) {
    int i = blockIdx.x * 256 + threadIdx.x;
    if (i < 16384) {
        int nn = i >> 7, k = i & 127;
        Wt0[i] = f2b(W0[k * 128 + nn]);
    } else if (i < 32768) {
        int j = i - 16384; int nn = j >> 7, k = j & 127;
        Wt1[j] = f2b(W1[k * 128 + nn]);
    } else if (i < 49152) {
        int j = i - 32768; int nn = j >> 7, k = j & 127;
        Wt2[j] = f2b(W2[k * 128 + nn]);
    } else if (i < 57344) {
        int j = i - 49152; int nn = j >> 7, k = j & 127;
        Wto[j] = f2b(Wo[k * 64 + nn]);
    }
}

// ---------------- MFMA GEMM: C[n x NCOL] = A[n x 128] @ Wt^T ----------------
// 2 row-tiles (32 rows) per wave, 128 rows per block.

template <int NCOL, bool IN_F32, bool OUT_F32>
__global__ __launch_bounds__(256) void k_mm(const void* __restrict__ Av,
                                            const ushort* __restrict__ Wt,
                                            const float* __restrict__ bias,
                                            void* __restrict__ Cv, int n) {
    constexpr int NT = NCOL / 16;
    int wave = threadIdx.x >> 6;
    int lane = threadIdx.x & 63;
    int quad = lane >> 4;
    int lm = lane & 15;
    int row0 = blockIdx.x * 128 + wave * 32;

    int rA0 = row0 + lm;      if (rA0 > n - 1) rA0 = n - 1;
    int rA1 = row0 + 16 + lm; if (rA1 > n - 1) rA1 = n - 1;

    f32x4 acc[2][NT];
#pragma unroll
    for (int r = 0; r < 2; r++)
#pragma unroll
        for (int t = 0; t < NT; t++) acc[r][t] = (f32x4){0.f, 0.f, 0.f, 0.f};

    for (int kc = 0; kc < 128; kc += 32) {
        s8vec af[2];
        if (IN_F32) {
            const float* A = (const float*)Av;
#pragma unroll
            for (int r = 0; r < 2; r++) {
                const float* p = A + (size_t)(r ? rA1 : rA0) * 128 + quad * 8 + kc;
                float4 a = *(const float4*)p, b = *(const float4*)(p + 4);
                s8vec v;
                v[0] = (short)f2b(a.x); v[1] = (short)f2b(a.y);
                v[2] = (short)f2b(a.z); v[3] = (short)f2b(a.w);
                v[4] = (short)f2b(b.x); v[5] = (short)f2b(b.y);
                v[6] = (short)f2b(b.z); v[7] = (short)f2b(b.w);
                af[r] = v;
            }
        } else {
            const ushort* A = (const ushort*)Av;
            af[0] = *(const s8vec*)(A + (size_t)rA0 * 128 + quad * 8 + kc);
            af[1] = *(const s8vec*)(A + (size_t)rA1 * 128 + quad * 8 + kc);
        }
#pragma unroll
        for (int t = 0; t < NT; t++) {
            s8vec bf = *(const s8vec*)(Wt + (size_t)(t * 16 + lm) * 128 + kc + quad * 8);
            acc[0][t] = __builtin_amdgcn_mfma_f32_16x16x32_bf16(af[0], bf, acc[0][t], 0, 0, 0);
            acc[1][t] = __builtin_amdgcn_mfma_f32_16x16x32_bf16(af[1], bf, acc[1][t], 0, 0, 0);
        }
    }

    // C/D layout: col = lane&15, row = quad*4 + reg
#pragma unroll
    for (int r = 0; r < 2; r++) {
#pragma unroll
        for (int t = 0; t < NT; t++) {
            int col = t * 16 + lm;
            float bv = OUT_F32 ? bias[col] : 0.f;
#pragma unroll
            for (int i = 0; i < 4; i++) {
                int rr = row0 + r * 16 + quad * 4 + i;
                if (rr < n) {
                    if (OUT_F32)
                        ((float*)Cv)[(size_t)rr * NCOL + col] = acc[r][t][i] + bv;
                    else
                        ((ushort*)Cv)[(size_t)rr * 128 + col] = f2b(acc[r][t][i]);
                }
            }
        }
    }
}

// ---------------- fused gather (bf16 features, register-resident edge metadata) ----------------
// agg = sum_e T[src]*coef + T[node]*dinv^2 + bias; out = bf16(relu(agg) + res)

template <bool RES_F32>
__global__ __launch_bounds__(256) void k_gatherb(const uint* __restrict__ T,      // [n x 64] bf16-pairs
                                                 const int* __restrict__ rowptr,
                                                 const uint2* __restrict__ ed,
                                                 const float* __restrict__ dinv,
                                                 const float* __restrict__ bias,
                                                 const void* __restrict__ resv,
                                                 uint* __restrict__ out, int n) {
    int node = blockIdx.x * 4 + (threadIdx.x >> 6);
    if (node >= n) return;
    int lane = threadIdx.x & 63;

    int beg = rowptr[node], end = rowptr[node + 1];
    float ax = 0.f, ay = 0.f;

    for (int base = beg; base < end; base += 64) {
        int m = end - base; if (m > 64) m = 64;
        uint2 em = make_uint2(0u, 0u);
        if (base + lane < end) em = ed[base + lane];
        int j = 0;
        for (; j + 4 <= m; j += 4) {
            int s0 = __shfl((int)em.x, j);
            int s1 = __shfl((int)em.x, j + 1);
            int s2 = __shfl((int)em.x, j + 2);
            int s3 = __shfl((int)em.x, j + 3);
            float c0 = __int_as_float(__shfl((int)em.y, j));
            float c1 = __int_as_float(__shfl((int)em.y, j + 1));
            float c2 = __int_as_float(__shfl((int)em.y, j + 2));
            float c3 = __int_as_float(__shfl((int)em.y, j + 3));
            uint v0 = T[(size_t)s0 * 64 + lane];
            uint v1 = T[(size_t)s1 * 64 + lane];
            uint v2 = T[(size_t)s2 * 64 + lane];
            uint v3 = T[(size_t)s3 * 64 + lane];
            ax += b2f_lo(v0) * c0 + b2f_lo(v1) * c1 + b2f_lo(v2) * c2 + b2f_lo(v3) * c3;
            ay += b2f_hi(v0) * c0 + b2f_hi(v1) * c1 + b2f_hi(v2) * c2 + b2f_hi(v3) * c3;
        }
        for (; j < m; j++) {
            int s = __shfl((int)em.x, j);
            float c = __int_as_float(__shfl((int)em.y, j));
            uint v = T[(size_t)s * 64 + lane];
            ax += b2f_lo(v) * c;
            ay += b2f_hi(v) * c;
        }
    }

    float di = dinv[node];
    float sc = di * di;
    uint vs = T[(size_t)node * 64 + lane];
    float2 b = ((const float2*)bias)[lane];
    ax += b2f_lo(vs) * sc + b.x;
    ay += b2f_hi(vs) * sc + b.y;

    float rx, ry;
    if (RES_F32) {
        float2 rv = ((const float2*)resv)[(size_t)node * 64 + lane];
        rx = rv.x; ry = rv.y;
    } else {
        uint rv = ((const uint*)resv)[(size_t)node * 64 + lane];
        rx = b2f_lo(rv); ry = b2f_hi(rv);
    }
    float ox = fmaxf(ax, 0.f) + rx;
    float oy = fmaxf(ay, 0.f) + ry;
    out[(size_t)node * 64 + lane] = (uint)f2b(ox) | ((uint)f2b(oy) << 16);
}

// ---------------- launch ----------------

extern "C" void kernel_launch(void* const* d_in, const int* in_sizes, int n_in,
                              void* d_out, int out_size, void* d_ws, size_t ws_size,
                              hipStream_t stream) {
    const float* x  = (const float*)d_in[0];
    const int* eidx = (const int*)d_in[1];
    const float* W0 = (const float*)d_in[2];
    const float* b0 = (const float*)d_in[3];
    const float* W1 = (const float*)d_in[4];
    const float* b1 = (const float*)d_in[5];
    const float* W2 = (const float*)d_in[6];
    const float* b2 = (const float*)d_in[7];
    const float* Wo = (const float*)d_in[8];
    const float* bo = (const float*)d_in[9];
    float* out = (float*)d_out;

    const int N = N_NODES, E = N_EDGES;
    const int* srcI = eidx;
    const int* dstI = eidx + E;
    const int NB512 = cdiv(N, 512);  // 98 <= 128

    char* ws = (char*)d_ws;
    auto alloc = [&](size_t bytes) { char* p = ws; ws += (bytes + 255) / 256 * 256; return p; };
    int*    cnt    = (int*)alloc((size_t)N * 4);
    int*    cursor = (int*)alloc((size_t)N * 4);
    int*    rowptr = (int*)alloc((size_t)(N + 1) * 4);
    int*    bsum   = (int*)alloc((size_t)NB512 * 4);
    int*    boff   = (int*)alloc((size_t)NB512 * 4);
    float*  dinv   = (float*)alloc((size_t)N * 4);
    uint2*  ed     = (uint2*)alloc((size_t)E * 8);
    ushort* tmpb   = (ushort*)alloc((size_t)N * 128 * 2);
    ushort* hAb    = (ushort*)alloc((size_t)N * 128 * 2);
    ushort* hBb    = (ushort*)alloc((size_t)N * 128 * 2);
    ushort* Wt0    = (ushort*)alloc(128 * 128 * 2);
    ushort* Wt1    = (ushort*)alloc(128 * 128 * 2);
    ushort* Wt2    = (ushort*)alloc(128 * 128 * 2);
    ushort* Wto    = (ushort*)alloc(64 * 128 * 2);

    dim3 b256(256), b512(512);

    // degree + CSR build (+dinv) + weight prep
    k_zero_int<<<cdiv(N, 256), b256, 0, stream>>>(cnt, N);
    k_count<<<cdiv(E, 256), b256, 0, stream>>>(dstI, cnt, E);
    k_block_sum<<<NB512, b512, 0, stream>>>(cnt, bsum, N);
    k_scan_bsum<<<1, 128, 0, stream>>>(bsum, boff, NB512, rowptr, N, E);
    k_scan_block<<<NB512, b512, 0, stream>>>(cnt, boff, rowptr, cursor, dinv, N);
    k_fill<<<cdiv(E, 256), b256, 0, stream>>>(srcI, dstI, dinv, rowptr, cursor, ed, E);
    k_wt_all<<<cdiv(57344, 256), b256, 0, stream>>>(W0, W1, W2, Wo, Wt0, Wt1, Wt2, Wto);

    const int mmGrid = cdiv(N, 128);
    const int gGrid  = cdiv(N, 4);

    // layer 0 (fp32 input + fp32 residual)
    k_mm<128, true, false><<<mmGrid, b256, 0, stream>>>(x, Wt0, nullptr, tmpb, N);
    k_gatherb<true><<<gGrid, b256, 0, stream>>>((const uint*)tmpb, rowptr, ed, dinv, b0, x, (uint*)hAb, N);

    // layer 1
    k_mm<128, false, false><<<mmGrid, b256, 0, stream>>>(hAb, Wt1, nullptr, tmpb, N);
    k_gatherb<false><<<gGrid, b256, 0, stream>>>((const uint*)tmpb, rowptr, ed, dinv, b1, hAb, (uint*)hBb, N);

    // layer 2
    k_mm<128, false, false><<<mmGrid, b256, 0, stream>>>(hBb, Wt2, nullptr, tmpb, N);
    k_gatherb<false><<<gGrid, b256, 0, stream>>>((const uint*)tmpb, rowptr, ed, dinv, b2, hBb, (uint*)hAb, N);

    // output projection (fp32 out + bias)
    k_mm<64, false, true><<<mmGrid, b256, 0, stream>>>(hAb, Wto, bo, out, N);
}

// Round 5
// 312.097 us; speedup vs baseline: 4.8063x; 1.0835x over previous
//
#include <hip/hip_runtime.h>

#define N_NODES 50000
#define N_EDGES 800000

static inline int cdiv(int a, int b) { return (a + b - 1) / b; }

typedef __attribute__((ext_vector_type(8))) short s8vec;   // 8 x bf16 (4 VGPRs)
typedef __attribute__((ext_vector_type(4))) float f32x4;   // MFMA accumulator

// fp32 -> bf16 round-to-nearest-even
__device__ inline ushort f2b(float f) {
    uint u = __float_as_uint(f);
    uint r = (u + 0x7fffu + ((u >> 16) & 1u)) >> 16;
    return (ushort)r;
}
__device__ inline float b2f_lo(uint v) { return __uint_as_float(v << 16); }
__device__ inline float b2f_hi(uint v) { return __uint_as_float(v & 0xffff0000u); }

__device__ inline void acc8(float* acc, uint4 v, float c) {
    acc[0] += b2f_lo(v.x) * c; acc[1] += b2f_hi(v.x) * c;
    acc[2] += b2f_lo(v.y) * c; acc[3] += b2f_hi(v.y) * c;
    acc[4] += b2f_lo(v.z) * c; acc[5] += b2f_hi(v.z) * c;
    acc[6] += b2f_lo(v.w) * c; acc[7] += b2f_hi(v.w) * c;
}

// ---------------- prep: zero cnt ∥ weight transpose+convert ----------------
// blocks [0,196): cnt=0;  blocks [196,420): Wt[n*128+k] = bf16(W[k*Ncols+n])

__global__ __launch_bounds__(256) void k_prep(int* cnt,
                                              const float* __restrict__ W0, const float* __restrict__ W1,
                                              const float* __restrict__ W2, const float* __restrict__ Wo,
                                              ushort* Wt0, ushort* Wt1, ushort* Wt2, ushort* Wto) {
    int b = blockIdx.x;
    if (b < 196) {
        int i = b * 256 + threadIdx.x;
        if (i < N_NODES) cnt[i] = 0;
        return;
    }
    int i = (b - 196) * 256 + threadIdx.x;
    if (i < 16384) {
        int nn = i >> 7, k = i & 127;
        Wt0[i] = f2b(W0[k * 128 + nn]);
    } else if (i < 32768) {
        int j = i - 16384; int nn = j >> 7, k = j & 127;
        Wt1[j] = f2b(W1[k * 128 + nn]);
    } else if (i < 49152) {
        int j = i - 32768; int nn = j >> 7, k = j & 127;
        Wt2[j] = f2b(W2[k * 128 + nn]);
    } else if (i < 57344) {
        int j = i - 49152; int nn = j >> 7, k = j & 127;
        Wto[j] = f2b(Wo[k * 64 + nn]);
    }
}

__global__ __launch_bounds__(256) void k_count(const int* __restrict__ dst, int* cnt, int e) {
    int i = blockIdx.x * 256 + threadIdx.x;
    if (i < e) atomicAdd(&cnt[dst[i]], 1);
}

// ---------------- scan (CSR rowptr) ----------------

__global__ __launch_bounds__(512) void k_block_sum(const int* __restrict__ cnt, int* bsum, int n) {
    __shared__ int sh[512];
    int i = blockIdx.x * 512 + threadIdx.x;
    sh[threadIdx.x] = (i < n) ? cnt[i] : 0;
    __syncthreads();
    for (int off = 256; off > 0; off >>= 1) {
        if (threadIdx.x < off) sh[threadIdx.x] += sh[threadIdx.x + off];
        __syncthreads();
    }
    if (threadIdx.x == 0) bsum[blockIdx.x] = sh[0];
}

__global__ __launch_bounds__(128) void k_scan_bsum(const int* __restrict__ bsum, int* boff,
                                                   int nb, int* rowptr, int n, int e) {
    __shared__ int sh[128];
    int t = threadIdx.x;
    int v = (t < nb) ? bsum[t] : 0;
    sh[t] = v;
    __syncthreads();
    for (int off = 1; off < 128; off <<= 1) {
        int add = (t >= off) ? sh[t - off] : 0;
        __syncthreads();
        sh[t] += add;
        __syncthreads();
    }
    if (t < nb) boff[t] = sh[t] - v;
    if (t == 0) rowptr[n] = e;
}

__global__ __launch_bounds__(512) void k_scan_block(const int* __restrict__ cnt,
                                                    const int* __restrict__ boff,
                                                    int* rowptr, int* cursor, float* dinv, int n) {
    __shared__ int sh[512];
    int t = threadIdx.x;
    int i = blockIdx.x * 512 + t;
    int v = (i < n) ? cnt[i] : 0;
    sh[t] = v;
    __syncthreads();
    for (int off = 1; off < 512; off <<= 1) {
        int add = (t >= off) ? sh[t - off] : 0;
        __syncthreads();
        sh[t] += add;
        __syncthreads();
    }
    if (i < n) {
        rowptr[i] = sh[t] - v + boff[blockIdx.x];
        cursor[i] = 0;
        dinv[i] = rsqrtf((float)v + 1.0f);
    }
}

// ---------------- MFMA GEMM body (2 row-tiles / wave, 128 rows / block) ----------------

template <int NCOL, bool IN_F32, bool OUT_F32>
__device__ inline void mm_body(const void* __restrict__ Av, const ushort* __restrict__ Wt,
                               const float* __restrict__ bias, void* __restrict__ Cv,
                               int n, int bid) {
    constexpr int NT = NCOL / 16;
    int wave = threadIdx.x >> 6;
    int lane = threadIdx.x & 63;
    int quad = lane >> 4;
    int lm = lane & 15;
    int row0 = bid * 128 + wave * 32;

    int rA0 = row0 + lm;      if (rA0 > n - 1) rA0 = n - 1;
    int rA1 = row0 + 16 + lm; if (rA1 > n - 1) rA1 = n - 1;

    f32x4 acc[2][NT];
#pragma unroll
    for (int r = 0; r < 2; r++)
#pragma unroll
        for (int t = 0; t < NT; t++) acc[r][t] = (f32x4){0.f, 0.f, 0.f, 0.f};

    for (int kc = 0; kc < 128; kc += 32) {
        s8vec af[2];
        if (IN_F32) {
            const float* A = (const float*)Av;
#pragma unroll
            for (int r = 0; r < 2; r++) {
                const float* p = A + (size_t)(r ? rA1 : rA0) * 128 + quad * 8 + kc;
                float4 a = *(const float4*)p, b = *(const float4*)(p + 4);
                s8vec v;
                v[0] = (short)f2b(a.x); v[1] = (short)f2b(a.y);
                v[2] = (short)f2b(a.z); v[3] = (short)f2b(a.w);
                v[4] = (short)f2b(b.x); v[5] = (short)f2b(b.y);
                v[6] = (short)f2b(b.z); v[7] = (short)f2b(b.w);
                af[r] = v;
            }
        } else {
            const ushort* A = (const ushort*)Av;
            af[0] = *(const s8vec*)(A + (size_t)rA0 * 128 + quad * 8 + kc);
            af[1] = *(const s8vec*)(A + (size_t)rA1 * 128 + quad * 8 + kc);
        }
#pragma unroll
        for (int t = 0; t < NT; t++) {
            s8vec bf = *(const s8vec*)(Wt + (size_t)(t * 16 + lm) * 128 + kc + quad * 8);
            acc[0][t] = __builtin_amdgcn_mfma_f32_16x16x32_bf16(af[0], bf, acc[0][t], 0, 0, 0);
            acc[1][t] = __builtin_amdgcn_mfma_f32_16x16x32_bf16(af[1], bf, acc[1][t], 0, 0, 0);
        }
    }

    // C/D layout: col = lane&15, row = quad*4 + reg
#pragma unroll
    for (int r = 0; r < 2; r++) {
#pragma unroll
        for (int t = 0; t < NT; t++) {
            int col = t * 16 + lm;
            float bv = OUT_F32 ? bias[col] : 0.f;
#pragma unroll
            for (int i = 0; i < 4; i++) {
                int rr = row0 + r * 16 + quad * 4 + i;
                if (rr < n) {
                    if (OUT_F32)
                        ((float*)Cv)[(size_t)rr * NCOL + col] = acc[r][t][i] + bv;
                    else
                        ((ushort*)Cv)[(size_t)rr * 128 + col] = f2b(acc[r][t][i]);
                }
            }
        }
    }
}

template <int NCOL, bool IN_F32, bool OUT_F32>
__global__ __launch_bounds__(256) void k_mm(const void* __restrict__ Av,
                                            const ushort* __restrict__ Wt,
                                            const float* __restrict__ bias,
                                            void* __restrict__ Cv, int n) {
    mm_body<NCOL, IN_F32, OUT_F32>(Av, Wt, bias, Cv, n, blockIdx.x);
}

// fused: blocks [0,mmblocks) = layer-0 GEMM; rest = CSR fill (independent work)
__global__ __launch_bounds__(256) void k_mm0_fill(const void* __restrict__ Av,
                                                  const ushort* __restrict__ Wt,
                                                  void* __restrict__ Cv, int n, int mmblocks,
                                                  const int* __restrict__ src, const int* __restrict__ dst,
                                                  const float* __restrict__ dinv,
                                                  const int* __restrict__ rowptr, int* cursor,
                                                  uint2* ed, int e) {
    if ((int)blockIdx.x >= mmblocks) {
        int i = ((int)blockIdx.x - mmblocks) * 256 + threadIdx.x;
        if (i < e) {
            int d = dst[i], s = src[i];
            int pos = rowptr[d] + atomicAdd(&cursor[d], 1);
            float c = dinv[s] * dinv[d];
            ed[pos] = make_uint2((uint)s, __float_as_uint(c));
        }
        return;
    }
    mm_body<128, true, false>(Av, Wt, nullptr, Cv, n, blockIdx.x);
}

// ---------------- fused gather: 16 lanes per node, uint4 (16B) per lane ----------------
// out = bf16( relu( sum_e T[src]*coef + T[node]*dinv^2 + bias ) + res )

template <bool RES_F32>
__global__ __launch_bounds__(256) void k_gatherb(const uint4* __restrict__ T4,   // [n x 16] uint4
                                                 const int* __restrict__ rowptr,
                                                 const uint2* __restrict__ ed,
                                                 const float* __restrict__ dinv,
                                                 const float* __restrict__ bias,
                                                 const void* __restrict__ resv,
                                                 uint4* __restrict__ out4, int n) {
    int node = blockIdx.x * 16 + (threadIdx.x >> 4);
    if (node >= n) return;
    int ql = threadIdx.x & 15;
    int qb = threadIdx.x & 48;   // quarter base within the 64-lane wave

    float acc[8] = {0.f, 0.f, 0.f, 0.f, 0.f, 0.f, 0.f, 0.f};
    int beg = rowptr[node], end = rowptr[node + 1];

    for (int base = beg; base < end; base += 16) {
        int m = end - base; if (m > 16) m = 16;
        uint2 em = make_uint2(0u, 0u);
        if (base + ql < end) em = ed[base + ql];
        int j = 0;
        for (; j + 4 <= m; j += 4) {
            int s0 = __shfl((int)em.x, qb + j);
            int s1 = __shfl((int)em.x, qb + j + 1);
            int s2 = __shfl((int)em.x, qb + j + 2);
            int s3 = __shfl((int)em.x, qb + j + 3);
            float c0 = __uint_as_float((uint)__shfl((int)em.y, qb + j));
            float c1 = __uint_as_float((uint)__shfl((int)em.y, qb + j + 1));
            float c2 = __uint_as_float((uint)__shfl((int)em.y, qb + j + 2));
            float c3 = __uint_as_float((uint)__shfl((int)em.y, qb + j + 3));
            uint4 v0 = T4[(size_t)s0 * 16 + ql];
            uint4 v1 = T4[(size_t)s1 * 16 + ql];
            uint4 v2 = T4[(size_t)s2 * 16 + ql];
            uint4 v3 = T4[(size_t)s3 * 16 + ql];
            acc8(acc, v0, c0); acc8(acc, v1, c1);
            acc8(acc, v2, c2); acc8(acc, v3, c3);
        }
        for (; j < m; j++) {
            int s = __shfl((int)em.x, qb + j);
            float c = __uint_as_float((uint)__shfl((int)em.y, qb + j));
            uint4 v = T4[(size_t)s * 16 + ql];
            acc8(acc, v, c);
        }
    }

    float di = dinv[node];
    float sc = di * di;
    uint4 vs = T4[(size_t)node * 16 + ql];
    float self[8] = {b2f_lo(vs.x), b2f_hi(vs.x), b2f_lo(vs.y), b2f_hi(vs.y),
                     b2f_lo(vs.z), b2f_hi(vs.z), b2f_lo(vs.w), b2f_hi(vs.w)};
    float4 bv0 = ((const float4*)bias)[ql * 2];
    float4 bv1 = ((const float4*)bias)[ql * 2 + 1];
    float bb[8] = {bv0.x, bv0.y, bv0.z, bv0.w, bv1.x, bv1.y, bv1.z, bv1.w};

    float r[8];
    if (RES_F32) {
        float4 r0 = ((const float4*)resv)[(size_t)node * 32 + ql * 2];
        float4 r1 = ((const float4*)resv)[(size_t)node * 32 + ql * 2 + 1];
        r[0] = r0.x; r[1] = r0.y; r[2] = r0.z; r[3] = r0.w;
        r[4] = r1.x; r[5] = r1.y; r[6] = r1.z; r[7] = r1.w;
    } else {
        uint4 rv = ((const uint4*)resv)[(size_t)node * 16 + ql];
        r[0] = b2f_lo(rv.x); r[1] = b2f_hi(rv.x); r[2] = b2f_lo(rv.y); r[3] = b2f_hi(rv.y);
        r[4] = b2f_lo(rv.z); r[5] = b2f_hi(rv.z); r[6] = b2f_lo(rv.w); r[7] = b2f_hi(rv.w);
    }

    float o[8];
#pragma unroll
    for (int i = 0; i < 8; i++)
        o[i] = fmaxf(acc[i] + self[i] * sc + bb[i], 0.f) + r[i];

    uint4 ov;
    ov.x = (uint)f2b(o[0]) | ((uint)f2b(o[1]) << 16);
    ov.y = (uint)f2b(o[2]) | ((uint)f2b(o[3]) << 16);
    ov.z = (uint)f2b(o[4]) | ((uint)f2b(o[5]) << 16);
    ov.w = (uint)f2b(o[6]) | ((uint)f2b(o[7]) << 16);
    out4[(size_t)node * 16 + ql] = ov;
}

// ---------------- launch ----------------

extern "C" void kernel_launch(void* const* d_in, const int* in_sizes, int n_in,
                              void* d_out, int out_size, void* d_ws, size_t ws_size,
                              hipStream_t stream) {
    const float* x  = (const float*)d_in[0];
    const int* eidx = (const int*)d_in[1];
    const float* W0 = (const float*)d_in[2];
    const float* b0 = (const float*)d_in[3];
    const float* W1 = (const float*)d_in[4];
    const float* b1 = (const float*)d_in[5];
    const float* W2 = (const float*)d_in[6];
    const float* b2 = (const float*)d_in[7];
    const float* Wo = (const float*)d_in[8];
    const float* bo = (const float*)d_in[9];
    float* out = (float*)d_out;

    const int N = N_NODES, E = N_EDGES;
    const int* srcI = eidx;
    const int* dstI = eidx + E;
    const int NB512 = cdiv(N, 512);  // 98

    char* ws = (char*)d_ws;
    auto alloc = [&](size_t bytes) { char* p = ws; ws += (bytes + 255) / 256 * 256; return p; };
    int*    cnt    = (int*)alloc((size_t)N * 4);
    int*    cursor = (int*)alloc((size_t)N * 4);
    int*    rowptr = (int*)alloc((size_t)(N + 1) * 4);
    int*    bsum   = (int*)alloc((size_t)NB512 * 4);
    int*    boff   = (int*)alloc((size_t)NB512 * 4);
    float*  dinv   = (float*)alloc((size_t)N * 4);
    uint2*  ed     = (uint2*)alloc((size_t)E * 8);
    ushort* tmpb   = (ushort*)alloc((size_t)N * 128 * 2);
    ushort* hAb    = (ushort*)alloc((size_t)N * 128 * 2);
    ushort* hBb    = (ushort*)alloc((size_t)N * 128 * 2);
    ushort* Wt0    = (ushort*)alloc(128 * 128 * 2);
    ushort* Wt1    = (ushort*)alloc(128 * 128 * 2);
    ushort* Wt2    = (ushort*)alloc(128 * 128 * 2);
    ushort* Wto    = (ushort*)alloc(64 * 128 * 2);

    dim3 b256(256), b512(512);

    const int mmGrid = cdiv(N, 128);        // 391
    const int fillGrid = cdiv(E, 256);      // 3125
    const int gGrid = cdiv(N, 16);          // 3125

    // prep (zero cnt ∥ weight transpose), degree, CSR scan
    k_prep<<<196 + 224, b256, 0, stream>>>(cnt, W0, W1, W2, Wo, Wt0, Wt1, Wt2, Wto);
    k_count<<<cdiv(E, 256), b256, 0, stream>>>(dstI, cnt, E);
    k_block_sum<<<NB512, b512, 0, stream>>>(cnt, bsum, N);
    k_scan_bsum<<<1, 128, 0, stream>>>(bsum, boff, NB512, rowptr, N, E);
    k_scan_block<<<NB512, b512, 0, stream>>>(cnt, boff, rowptr, cursor, dinv, N);

    // layer-0 GEMM fused with CSR fill (independent)
    k_mm0_fill<<<mmGrid + fillGrid, b256, 0, stream>>>(x, Wt0, tmpb, N, mmGrid,
                                                       srcI, dstI, dinv, rowptr, cursor, ed, E);
    k_gatherb<true><<<gGrid, b256, 0, stream>>>((const uint4*)tmpb, rowptr, ed, dinv, b0, x, (uint4*)hAb, N);

    // layer 1
    k_mm<128, false, false><<<mmGrid, b256, 0, stream>>>(hAb, Wt1, nullptr, tmpb, N);
    k_gatherb<false><<<gGrid, b256, 0, stream>>>((const uint4*)tmpb, rowptr, ed, dinv, b1, hAb, (uint4*)hBb, N);

    // layer 2
    k_mm<128, false, false><<<mmGrid, b256, 0, stream>>>(hBb, Wt2, nullptr, tmpb, N);
    k_gatherb<false><<<gGrid, b256, 0, stream>>>((const uint4*)tmpb, rowptr, ed, dinv, b2, hBb, (uint4*)hAb, N);

    // output projection (fp32 out + bias)
    k_mm<64, false, true><<<mmGrid, b256, 0, stream>>>(hAb, Wto, bo, out, N);
}